// Round 12
// baseline (220.378 us; speedup 1.0000x reference)
//
#include <hip/hip_runtime.h>
#include <math.h>

#define B  8
#define T  16
#define C  64
#define H  56
#define W  56
#define HW (H*W)          // 3136 floats per (n,t) slice
#define HW4 (HW/4)        // 784 float4
#define CHUNK 196         // float4 cols per chunk = 14 rows = 2 window-rows
#define NCHUNK 4
#define CELEM (16*CHUNK)  // 3136 float4 per chunk (16 slices)
#define DIN 64
#define DOUT 32
#define BC (B*C)          // 512

// ---------------------------------------------------------------------------
// R11 -> R12: cross-round accounting shows EVERY x-touching pass runs at
// ~2.5 TB/s (pool ~39 us, apply ~40 us, R11 fused 82.4) while write-only
// fills hit 6.8 and the copy ubench 6.29 -> suspected L3-writeback
// contention from the harness re-poison (invisible to TCC). The remaining
// in-kernel waste is R11's 8 serial phases each paying a full vmcnt(0)
// drain at the stage barrier. Fix = T14 reg-staged pipelining: issue chunk
// g+1's global loads into REGISTERS before computing chunk g; ds_write them
// next phase (waitcnt satisfied by register dependency during compute, not
// at a barrier). Apply-chunk-0 loads are issued before the att phase so
// q/k/softmax hides them. Geometry unchanged (512 blocks x 1024 thr,
// ~66 KB LDS -> 2 blocks/CU); staging adds ~16 VGPR (R11 was 24 -> ~40,
// still <=64 so 8 waves/SIMD holds).
// ---------------------------------------------------------------------------
__global__ __launch_bounds__(1024, 8) void fused_kernel(const float* __restrict__ x,
                                                        const float* __restrict__ Wq,
                                                        const float* __restrict__ bq,
                                                        const float* __restrict__ Wk,
                                                        const float* __restrict__ bk,
                                                        float* __restrict__ out) {
    __shared__ float xs[CELEM * 4];          // 16 slices x 784 floats = 50176 B
    __shared__ float part[1024];             // 4 KB pool partials
    __shared__ float pooled_s[T * DIN];      // 4 KB
    __shared__ float qs[T * 33];             // padded
    __shared__ float ksh[T * 33];
    __shared__ float att_s[T * T];           // logits
    __shared__ float att_tr[T * T];          // probs transposed [s][t]

    const int n = blockIdx.x;                // b*C + c
    const int tid = threadIdx.x;
    const int b = n >> 6;
    const int c = n & 63;

    const float4* x4 = (const float4*)x;
    float4* o4 = (float4*)out;
    float4* xs4 = (float4*)xs;
    const size_t base = ((size_t)(b * T) * C + c) * HW4;   // + s*tstr + col
    const size_t tstr = (size_t)C * HW4;                   // 50176 float4

    // flat chunk element i (0..3135) -> slice s = i/CHUNK, col off = i%CHUNK
    // per-thread elements: i = tid + k*1024, k=0..2 full, k=3 only tid<64.
    const int i0 = tid;
    const int i1 = tid + 1024;
    const int i2 = tid + 2048;
    const int i3 = tid + 3072;               // valid iff tid < 64
    const int s0 = i0 / CHUNK, f0 = i0 - s0 * CHUNK;
    const int s1 = i1 / CHUNK, f1 = i1 - s1 * CHUNK;
    const int s2 = i2 / CHUNK, f2 = i2 - s2 * CHUNK;
    const int s3 = i3 / CHUNK, f3 = i3 - s3 * CHUNK;

    float4 r0, r1, r2, r3;                   // in-flight staging registers

    // issue chunk g's loads into regs (no LDS touch, no barrier needed)
    auto issue = [&](int g) {
        const int gc = g * CHUNK;
        r0 = x4[base + (size_t)s0 * tstr + gc + f0];
        r1 = x4[base + (size_t)s1 * tstr + gc + f1];
        r2 = x4[base + (size_t)s2 * tstr + gc + f2];
        if (tid < 64) r3 = x4[base + (size_t)s3 * tstr + gc + f3];
    };
    // commit staged regs to LDS (s_waitcnt via register dependency)
    auto commit = [&]() {
        xs4[i0] = r0;
        xs4[i1] = r1;
        xs4[i2] = r2;
        if (tid < 64) xs4[i3] = r3;
    };

    // ================= pass 1: pool, software-pipelined ==================
    issue(0);
    #pragma unroll 1
    for (int g = 0; g < NCHUNK; ++g) {
        commit();                            // write chunk g to LDS
        __syncthreads();
        if (g + 1 < NCHUNK) issue(g + 1);    // next chunk in flight over reduce
        // reduce: 256 windows (16 slices x 2 wrows x 8 wcols), 4 thr/window
        {
            const int q  = tid >> 8;         // row-group: {0,1}{2,3}{4,5}{6}
            const int wi = tid & 255;
            const int sl = wi >> 4;
            const int w8 = wi & 15;          // wrow*8 + wcol
            const int wrow = w8 >> 3;
            const int wcol = w8 & 7;
            const int r0i = 2 * q;
            const int nr = (q < 3) ? 2 : 1;
            float s = 0.f;
            for (int dr = 0; dr < nr; ++dr) {
                const int row = wrow * 7 + r0i + dr;         // 0..13 in chunk
                const int fbase = sl * (CHUNK * 4) + row * W + wcol * 7;
                #pragma unroll
                for (int j = 0; j < 7; ++j) s += xs[fbase + j];
            }
            part[q * 256 + wi] = s;
        }
        __syncthreads();                     // part ready; xs readers done
        if (tid < 256) {
            const int sl = tid >> 4;
            const int w8 = tid & 15;
            const float v = part[tid] + part[tid + 256] + part[tid + 512] + part[tid + 768];
            pooled_s[sl * DIN + g * 16 + w8] = v * (1.0f / 49.0f);
        }
        // next commit() races nothing: xs readers passed the barrier above;
        // part is re-read only after the NEXT barrier.
    }
    __syncthreads();                         // pooled_s complete

    issue(0);                                // apply chunk 0 hides under att

    // ================= q/k + logits + softmax (in-LDS, brief) ============
    if (tid < T * DOUT) {
        const int t = tid >> 5;
        const int d = tid & 31;
        float sq = bq[d];
        float sk = bk[d];
        #pragma unroll 8
        for (int kk = 0; kk < DIN; ++kk) {
            const float f = pooled_s[t * DIN + kk];
            sq = fmaf(f, Wq[kk * DOUT + d], sq);
            sk = fmaf(f, Wk[kk * DOUT + d], sk);
        }
        qs[t * 33 + d] = sq;
        ksh[t * 33 + d] = sk;
    }
    __syncthreads();

    if (tid < T * T) {
        const int tt = tid >> 4;
        const int ss = tid & 15;
        float s = 0.f;
        #pragma unroll
        for (int d = 0; d < DOUT; ++d) s = fmaf(qs[tt * 33 + d], ksh[ss * 33 + d], s);
        att_s[tid] = s * 0.25f;              // 1/sqrt(16)
    }
    __syncthreads();

    if (tid < T) {
        const int r = tid;
        float m = -INFINITY;
        #pragma unroll
        for (int s = 0; s < T; ++s) m = fmaxf(m, att_s[r * T + s]);
        float e[T];
        float sum = 0.f;
        #pragma unroll
        for (int s = 0; s < T; ++s) { e[s] = __expf(att_s[r * T + s] - m); sum += e[s]; }
        const float inv = 1.0f / sum;
        #pragma unroll
        for (int s = 0; s < T; ++s) att_tr[s * T + r] = e[s] * inv;
    }
    __syncthreads();

    // ================= pass 2: apply, software-pipelined =================
    #pragma unroll 1
    for (int g = 0; g < NCHUNK; ++g) {
        commit();                            // write chunk g (loads long since done)
        __syncthreads();
        if (g + 1 < NCHUNK) issue(g + 1);    // next chunk (L3-hot) in flight
        // compute+store: element i -> t = i/CHUNK, col = i%CHUNK
        {
            const int gc = g * CHUNK;
            // k = 0..2 full, k = 3 only tid < 64 (same mapping as staging)
            #pragma unroll
            for (int k = 0; k < 3; ++k) {
                const int i   = tid + k * 1024;
                const int t   = i / CHUNK;
                const int col = i - t * CHUNK;
                float4 a = make_float4(0.f, 0.f, 0.f, 0.f);
                #pragma unroll 4
                for (int s = 0; s < T; ++s) {
                    const float w = att_tr[s * T + t];
                    const float4 xv = xs4[s * CHUNK + col];
                    a.x = fmaf(w, xv.x, a.x);
                    a.y = fmaf(w, xv.y, a.y);
                    a.z = fmaf(w, xv.z, a.z);
                    a.w = fmaf(w, xv.w, a.w);
                }
                o4[base + (size_t)t * tstr + gc + col] = a;
            }
            if (tid < 64) {
                const int i   = tid + 3072;
                const int t   = i / CHUNK;
                const int col = i - t * CHUNK;
                float4 a = make_float4(0.f, 0.f, 0.f, 0.f);
                #pragma unroll 4
                for (int s = 0; s < T; ++s) {
                    const float w = att_tr[s * T + t];
                    const float4 xv = xs4[s * CHUNK + col];
                    a.x = fmaf(w, xv.x, a.x);
                    a.y = fmaf(w, xv.y, a.y);
                    a.z = fmaf(w, xv.z, a.z);
                    a.w = fmaf(w, xv.w, a.w);
                }
                o4[base + (size_t)t * tstr + gc + col] = a;
            }
        }
        __syncthreads();                     // xs readers done before next commit
    }
}

extern "C" void kernel_launch(void* const* d_in, const int* in_sizes, int n_in,
                              void* d_out, int out_size, void* d_ws, size_t ws_size,
                              hipStream_t stream) {
    const float* x  = (const float*)d_in[0];
    const float* Wq = (const float*)d_in[1];
    const float* bq = (const float*)d_in[2];
    const float* Wk = (const float*)d_in[3];
    const float* bk = (const float*)d_in[4];
    float* out = (float*)d_out;

    fused_kernel<<<dim3(BC), dim3(1024), 0, stream>>>(x, Wq, bq, Wk, bk, out);
}